// Round 9
// baseline (5958.983 us; speedup 1.0000x reference)
//
#include <hip/hip_runtime.h>

#define T_STEPS 4096
#define M_BATCH 512
#define D_INP   11
#define N_HID   51
#define ACTS    140     // act row stride (ushorts): 280B -> dword bank-stride 6, conflict-free

typedef __attribute__((ext_vector_type(8))) short bf16x8;   // MFMA A/B frag (8 bf16)
typedef __attribute__((ext_vector_type(4))) float f32x4;    // MFMA C/D frag
typedef __attribute__((ext_vector_type(4))) short s16x4;

__device__ __forceinline__ float sigmoid_fast(float v) {
    return __builtin_amdgcn_rcpf(1.0f + __expf(-v));
}
__device__ __forceinline__ float tanh_fast(float v) {
    return 2.0f * __builtin_amdgcn_rcpf(1.0f + __expf(-2.0f * v)) - 1.0f;
}
__device__ __forceinline__ ushort f2bf(float f) {          // fp32 -> bf16 RNE
    uint u = __float_as_uint(f);
    u += 0x7fffu + ((u >> 16) & 1u);
    return (ushort)(u >> 16);
}
__device__ __forceinline__ float bf2f(ushort h) {
    return __uint_as_float(((uint)h) << 16);
}

#define MFMA(A,B,C) __builtin_amdgcn_mfma_f32_16x16x32_bf16((A),(B),(C),0,0,0)

// MFMA 2-layer LSTM, 16-wave 1-barrier schedule.  One block = 16 batch
// columns, grid=32.  DATAPATH identical to the r7/r8 PASSING kernels
// (hi+lo bf16 weight split, verified A/B/C-D fragment mappings, W_lin as
// row 204 of L2).  Structure: (1) 16 waves -> 4 waves/SIMD TLP, per-wave
// work halved (1-2 tiles); (2) act LDS parity-double-buffered -> ONE
// barrier/step is race-free: phase B uses only the wave's own acc/cst,
// and with a barrier every step all waves are in the same step, where
// reads hit act[t&1] and writes hit act[(t+1)&1] (disjoint); (3) merged
// h1/h2 act array (h1 slots 0..50, h2 51..101; L1's k=63 pad aliases
// h2[0] but the A-operand is 0 there so the product is 0).
// Tiles: L1 13 tiles over w0-w7 (w0-4: 2 tiles, w5-7: 1), L2 13 over
// w8-w15 (w8-12: 2, w13-15: 1; w15 tile 12 has proj row 204).
// L2 lags L1 by one step.  Flush reads outb slots t-35..t-4 (writers
// touch only t-3..t-1 within the step) + 33-slot tail.
__attribute__((amdgpu_waves_per_eu(4, 4)))
__global__ __launch_bounds__(1024)
void lstm2_mfma16(const float* __restrict__ input,
                  const float* __restrict__ W_ih1, const float* __restrict__ W_hh1,
                  const float* __restrict__ b_ih1, const float* __restrict__ b_hh1,
                  const float* __restrict__ W_ih2, const float* __restrict__ W_hh2,
                  const float* __restrict__ b_ih2, const float* __restrict__ b_hh2,
                  const float* __restrict__ W_lin, const float* __restrict__ b_lin,
                  float* __restrict__ out)
{
    const int tid  = threadIdx.x;
    const int wid  = tid >> 6;
    const int lane = tid & 63;
    const int mr   = lane & 15;      // A row-in-tile; also the batch column (C/D col)
    const int g    = lane >> 4;      // k-group; C/D row block
    const int col0 = blockIdx.x * 16;
    const bool isL1 = wid < 8;
    const int  lw   = isL1 ? wid : wid - 8;
    const int  m0   = (lw < 5) ? lw * 2 : 10 + (lw - 5);   // first owned tile

    __shared__ __align__(16) ushort act[2][16][ACTS];   // [parity][col][k]: h1 0..50, h2 51..101
    __shared__ __align__(16) ushort xck[2][16][16][12]; // [buf][step][col][d]
    __shared__ __align__(16) float  outb[16][64];       // [col][slot]

    // ---------------- LDS zero-init ----------------
    for (int i = tid; i < 2 * 16 * ACTS; i += 1024) (&act[0][0][0])[i] = 0;
    for (int i = tid; i < 2 * 16 * 16 * 12; i += 1024) (&xck[0][0][0][0])[i] = 0;
    for (int i = tid; i < 16 * 64; i += 1024) (&outb[0][0])[i] = 0.f;

    // ---------------- x staging: issue-early / write-late ----------------
    float xr[3];
    auto xissue = [&](int cn) {                       // 2816 fp32 elems / chunk
        #pragma unroll
        for (int i = 0; i < 3; ++i) {
            int f = i * 1024 + tid;
            if (f < 2816) {
                int s = f / 176, r2 = f - s * 176;
                int cc = r2 / 11, d = r2 - cc * 11;
                int ts = cn * 16 + s; if (ts > T_STEPS - 1) ts = T_STEPS - 1;
                xr[i] = input[((size_t)ts * M_BATCH + col0 + cc) * D_INP + d];
            }
        }
    };
    auto xwrite = [&](int cn) {
        #pragma unroll
        for (int i = 0; i < 3; ++i) {
            int f = i * 1024 + tid;
            if (f < 2816) {
                int s = f / 176, r2 = f - s * 176;
                int cc = r2 / 11, d = r2 - cc * 11;
                xck[cn & 1][s][cc][d] = f2bf(xr[i]);
            }
        }
    };

    // ---------------- persistent A-fragments (weights, hi+lo) ----------------
    auto wgetL1 = [&](int r, int k) -> float {
        if (r >= 204) return 0.f;
        int u = r >> 2, q = r & 3;
        if (k < 12) return (k < 11) ? W_ih1[(q * 51 + u) * 11 + k] : 0.f;
        int hu = k - 12; return (hu < 51) ? W_hh1[(q * 51 + u) * 51 + hu] : 0.f;
    };
    auto wgetL2 = [&](int r, int k) -> float {
        if (r == 204) return (k >= 51 && k < 102) ? W_lin[k - 51] : 0.f;
        if (r > 204) return 0.f;
        int u = r >> 2, q = r & 3;
        if (k < 51)  return W_ih2[(q * 51 + u) * 51 + k];
        if (k < 102) return W_hh2[(q * 51 + u) * 51 + (k - 51)];
        return 0.f;
    };
    // A layout (verified r7): lane holds A[16m+mr][k], k = 32kt + 16*(j>>2) + 4g + (j&3)
    auto mkfragL1 = [&](int m, int kt, int ver) -> bf16x8 {
        bf16x8 fr;
        #pragma unroll
        for (int j = 0; j < 8; ++j) {
            int k = 32 * kt + 16 * (j >> 2) + 4 * g + (j & 3);
            float w = wgetL1(16 * m + mr, k);
            ushort hi = f2bf(w);
            fr[j] = (short)((ver == 0) ? hi : f2bf(w - bf2f(hi)));
        }
        return fr;
    };
    auto mkfragL2 = [&](int m, int kt, int ver) -> bf16x8 {
        bf16x8 fr;
        #pragma unroll
        for (int j = 0; j < 8; ++j) {
            int k = 32 * kt + 16 * (j >> 2) + 4 * g + (j & 3);
            float w = wgetL2(16 * m + mr, k);
            ushort hi = f2bf(w);
            fr[j] = (short)((ver == 0) ? hi : f2bf(w - bf2f(hi)));
        }
        return fr;
    };

    bf16x8 afr[16];
    if (isL1) {
        if (lw < 5) {
            #pragma unroll
            for (int mt = 0; mt < 2; ++mt)
                #pragma unroll
                for (int kt = 0; kt < 2; ++kt)
                    #pragma unroll
                    for (int v = 0; v < 2; ++v)
                        afr[(mt * 2 + kt) * 2 + v] = mkfragL1(m0 + mt, kt, v);
        } else {
            #pragma unroll
            for (int kt = 0; kt < 2; ++kt)
                #pragma unroll
                for (int v = 0; v < 2; ++v)
                    afr[kt * 2 + v] = mkfragL1(m0, kt, v);
        }
    } else {
        if (lw < 5) {
            #pragma unroll
            for (int mt = 0; mt < 2; ++mt)
                #pragma unroll
                for (int kt = 0; kt < 4; ++kt)
                    #pragma unroll
                    for (int v = 0; v < 2; ++v)
                        afr[(mt * 4 + kt) * 2 + v] = mkfragL2(m0 + mt, kt, v);
        } else {
            #pragma unroll
            for (int kt = 0; kt < 4; ++kt)
                #pragma unroll
                for (int v = 0; v < 2; ++v)
                    afr[kt * 2 + v] = mkfragL2(m0, kt, v);
        }
    }

    // ---------------- biases in registers (unit u = 4m+g) ----------------
    f32x4 br[2];
    #pragma unroll
    for (int mt = 0; mt < 2; ++mt) {
        int u = 4 * (m0 + mt) + g;
        f32x4 b = {0.f, 0.f, 0.f, 0.f};
        if (u < N_HID) {
            #pragma unroll
            for (int q = 0; q < 4; ++q)
                b[q] = isL1 ? (b_ih1[q * 51 + u] + b_hh1[q * 51 + u])
                            : (b_ih2[q * 51 + u] + b_hh2[q * 51 + u]);
        } else if (!isL1 && u == N_HID) {
            b[0] = b_lin[0];                           // proj row 204
        }
        br[mt] = b;
    }

    f32x4 acc[2];
    float cst[2] = {0.f, 0.f};

    auto lstm = [&](f32x4 gg, float& cs) -> float {
        float iv = sigmoid_fast(gg.x), fv = sigmoid_fast(gg.y);
        float gv = tanh_fast(gg.z),    ov = sigmoid_fast(gg.w);
        cs = fv * cs + iv * gv;
        return ov * tanh_fast(cs);
    };

    xissue(0);
    __syncthreads();                                   // zero-init visible
    xwrite(0);
    __syncthreads();                                   // chunk 0 visible

    #pragma unroll 1
    for (int t = 0; t <= T_STEPS + 1; ++t) {
        const int p = t & 1, q = p ^ 1;
        const int xb = (t >> 4) & 1, xst = t & 15;

        if ((t & 15) == 2 && t <= T_STEPS - 14) xissue((t >> 4) + 1);

        // B layout (verified r7): lane holds B[k][mr], k = 32kt + 16*(j>>2) + 4g + (j&3)
        auto loadB1 = [&](int kt) -> bf16x8 {          // L1: k<12 = x, 12..62 = h1
            int k0 = 32 * kt + 4 * g;
            const ushort* pa = (k0 < 12) ? &xck[xb][xst][mr][k0] : &act[p][mr][k0 - 12];
            s16x4 va = *(const s16x4*)pa;
            s16x4 vb = *(const s16x4*)&act[p][mr][k0 + 4];     // slot (k0+16)-12
            bf16x8 r;
            r[0]=va[0]; r[1]=va[1]; r[2]=va[2]; r[3]=va[3];
            r[4]=vb[0]; r[5]=vb[1]; r[6]=vb[2]; r[7]=vb[3];
            return r;
        };
        auto loadB2 = [&](int kt) -> bf16x8 {          // L2: k<51 = h1, 51..101 = h2
            int k0 = 32 * kt + 4 * g;
            s16x4 va = *(const s16x4*)&act[p][mr][k0];
            s16x4 vb = *(const s16x4*)&act[p][mr][k0 + 16];
            bf16x8 r;
            r[0]=va[0]; r[1]=va[1]; r[2]=va[2]; r[3]=va[3];
            r[4]=vb[0]; r[5]=vb[1]; r[6]=vb[2]; r[7]=vb[3];
            return r;
        };

        // ================= phase A: MFMA gate GEMMs =================
        if (isL1) {
            bf16x8 b0 = loadB1(0), b1 = loadB1(1);
            if (lw < 5) {
                #pragma unroll
                for (int mt = 0; mt < 2; ++mt) {
                    f32x4 aH = {0.f,0.f,0.f,0.f}, aL = {0.f,0.f,0.f,0.f};
                    aH = MFMA(afr[(mt*2+0)*2+0], b0, aH);
                    aH = MFMA(afr[(mt*2+1)*2+0], b1, aH);
                    aL = MFMA(afr[(mt*2+0)*2+1], b0, aL);
                    aL = MFMA(afr[(mt*2+1)*2+1], b1, aL);
                    acc[mt] = aH + aL;
                }
            } else {
                f32x4 aH = {0.f,0.f,0.f,0.f}, aL = {0.f,0.f,0.f,0.f};
                aH = MFMA(afr[0*2+0], b0, aH);
                aH = MFMA(afr[1*2+0], b1, aH);
                aL = MFMA(afr[0*2+1], b0, aL);
                aL = MFMA(afr[1*2+1], b1, aL);
                acc[0] = aH + aL;
            }
        } else {
            bf16x8 c0 = loadB2(0), c1 = loadB2(1), c2 = loadB2(2), c3 = loadB2(3);
            if (lw < 5) {
                #pragma unroll
                for (int mt = 0; mt < 2; ++mt) {
                    f32x4 aH = {0.f,0.f,0.f,0.f}, aL = {0.f,0.f,0.f,0.f};
                    aH = MFMA(afr[(mt*4+0)*2+0], c0, aH);
                    aH = MFMA(afr[(mt*4+1)*2+0], c1, aH);
                    aH = MFMA(afr[(mt*4+2)*2+0], c2, aH);
                    aH = MFMA(afr[(mt*4+3)*2+0], c3, aH);
                    aL = MFMA(afr[(mt*4+0)*2+1], c0, aL);
                    aL = MFMA(afr[(mt*4+1)*2+1], c1, aL);
                    aL = MFMA(afr[(mt*4+2)*2+1], c2, aL);
                    aL = MFMA(afr[(mt*4+3)*2+1], c3, aL);
                    acc[mt] = aH + aL;
                }
            } else {
                f32x4 aH = {0.f,0.f,0.f,0.f}, aL = {0.f,0.f,0.f,0.f};
                aH = MFMA(afr[0*2+0], c0, aH);
                aH = MFMA(afr[1*2+0], c1, aH);
                aH = MFMA(afr[2*2+0], c2, aH);
                aH = MFMA(afr[3*2+0], c3, aH);
                aL = MFMA(afr[0*2+1], c0, aL);
                aL = MFMA(afr[1*2+1], c1, aL);
                aL = MFMA(afr[2*2+1], c2, aL);
                aL = MFMA(afr[3*2+1], c3, aL);
                acc[0] = aH + aL;
            }
        }

        // ======= phase B: lane-local state updates -> act[q] (no barrier needed:
        // reads hit act[p], writes act[q]; acc/cst are this wave's registers) =======
        if (isL1) {
            if (lw < 5) {                              // u = 4m+g <= 39: no guard
                #pragma unroll
                for (int mt = 0; mt < 2; ++mt) {
                    f32x4 gg = acc[mt] + br[mt];
                    float h = lstm(gg, cst[mt]);
                    act[q][mr][4 * (m0 + mt) + g] = f2bf(h);
                }
            } else {                                   // m0 in {10,11,12}: u up to 51
                int u = 4 * m0 + g;
                f32x4 gg = acc[0] + br[0];
                float h = lstm(gg, cst[0]);
                if (u < N_HID) act[q][mr][u] = f2bf(h);
            }
        } else {
            if (t >= 1) {
                if (lw < 5) {                          // u <= 39
                    #pragma unroll
                    for (int mt = 0; mt < 2; ++mt) {
                        f32x4 gg = acc[mt] + br[mt];
                        float h = lstm(gg, cst[mt]);
                        act[q][mr][N_HID + 4 * (m0 + mt) + g] = f2bf(h);
                    }
                } else {                               // u = 40..51 (51 = proj row)
                    int u = 4 * m0 + g;
                    f32x4 gg = acc[0] + br[0];
                    if (u < N_HID) {
                        float h = lstm(gg, cst[0]);
                        act[q][mr][N_HID + u] = f2bf(h);
                    } else if (u == N_HID && t >= 2) { // out(t-2), bias included
                        outb[mr][(t - 2) & 63] = gg.x;
                    }
                }
            }
        }

        if ((t & 15) == 10 && t <= T_STEPS - 6) xwrite((t >> 4) + 1);

        if ((t & 31) == 2 && t >= 34 && tid < 512) {   // flush outputs t-35..t-4
            int cc = tid >> 5, s = tid & 31;
            int tb = t - 35 + s;
            if (tb >= 0) out[(size_t)(col0 + cc) * T_STEPS + tb] = outb[cc][tb & 63];
        }
        __syncthreads();                               // THE one barrier per step
    }

    if (tid < 528) {                                   // tail: outputs 4063..4095
        int cc = tid / 33, s = tid - cc * 33;
        int tb = 4063 + s;
        out[(size_t)(col0 + cc) * T_STEPS + tb] = outb[cc][tb & 63];
    }
}

extern "C" void kernel_launch(void* const* d_in, const int* in_sizes, int n_in,
                              void* d_out, int out_size, void* d_ws, size_t ws_size,
                              hipStream_t stream) {
    const float* input = (const float*)d_in[0];
    const float* W_ih1 = (const float*)d_in[1];
    const float* W_hh1 = (const float*)d_in[2];
    const float* b_ih1 = (const float*)d_in[3];
    const float* b_hh1 = (const float*)d_in[4];
    const float* W_ih2 = (const float*)d_in[5];
    const float* W_hh2 = (const float*)d_in[6];
    const float* b_ih2 = (const float*)d_in[7];
    const float* b_hh2 = (const float*)d_in[8];
    const float* W_lin = (const float*)d_in[9];
    const float* b_lin = (const float*)d_in[10];
    float* out = (float*)d_out;

    lstm2_mfma16<<<M_BATCH / 16, 1024, 0, stream>>>(
        input, W_ih1, W_hh1, b_ih1, b_hh1,
        W_ih2, W_hh2, b_ih2, b_hh2, W_lin, b_lin, out);
}